// Round 6
// baseline (426.102 us; speedup 1.0000x reference)
//
#include <hip/hip_runtime.h>
#include <hip/hip_bf16.h>

#define NN 2048
#define BB 8
#define FD 256
#define NEG_SLOPE 0.2f
#define EPSV 1e-7f

typedef __bf16 bf16x8 __attribute__((ext_vector_type(8)));
typedef __bf16 bf16x4 __attribute__((ext_vector_type(4)));
typedef float f32x4 __attribute__((ext_vector_type(4)));

// ---------------- K1: WT[o][f] = bf16(W[f][o]) ----------------
__global__ __launch_bounds__(256) void k1_prep(const float* __restrict__ W,
                                               __bf16* __restrict__ WT) {
    int idx = blockIdx.x * 256 + threadIdx.x;   // 256 blocks
    int o = idx >> 8, f = idx & 255;
    WT[idx] = (__bf16)W[f * FD + o];
}

// ---------------- K2: Wh = x @ W (bf16 MFMA) ----------------
__global__ __launch_bounds__(256) void k2_whgemm(const float* __restrict__ x,
                                                 const __bf16* __restrict__ WT,
                                                 float* __restrict__ Wh) {
    const int wave = threadIdx.x >> 6;
    const int lane = threadIdx.x & 63;
    const int row0 = blockIdx.x * 32 + (wave >> 1) * 16;
    const int ohalf = (wave & 1) * 128;
    const int m = lane & 15;
    const int quad = lane >> 4;
    const int row = row0 + m;
    const float* xrow = x + (size_t)row * FD + quad * 8;

    f32x4 acc[8];
#pragma unroll
    for (int n = 0; n < 8; ++n) acc[n] = (f32x4){0.f, 0.f, 0.f, 0.f};

    for (int k0 = 0; k0 < FD; k0 += 32) {
        float4 xa = *(const float4*)(xrow + k0);
        float4 xb = *(const float4*)(xrow + k0 + 4);
        bf16x8 af;
        af[0] = (__bf16)xa.x; af[1] = (__bf16)xa.y; af[2] = (__bf16)xa.z; af[3] = (__bf16)xa.w;
        af[4] = (__bf16)xb.x; af[5] = (__bf16)xb.y; af[6] = (__bf16)xb.z; af[7] = (__bf16)xb.w;
#pragma unroll
        for (int n = 0; n < 8; ++n) {
            int o = ohalf + n * 16 + m;
            bf16x8 bf = *(const bf16x8*)(WT + o * FD + k0 + quad * 8);
            acc[n] = __builtin_amdgcn_mfma_f32_16x16x32_bf16(af, bf, acc[n], 0, 0, 0);
        }
    }
#pragma unroll
    for (int n = 0; n < 8; ++n) {
        int o = ohalf + n * 16 + m;
#pragma unroll
        for (int r = 0; r < 4; ++r) {
            Wh[(size_t)(row0 + quad * 4 + r) * FD + o] = acc[n][r];
        }
    }
}

// ---------------- K3: s_src / s_dst ----------------
__global__ __launch_bounds__(256) void k3_scores(const float* __restrict__ Wh,
                                                 const float* __restrict__ a_w,
                                                 float* __restrict__ s_src,
                                                 float* __restrict__ s_dst) {
    int wave = threadIdx.x >> 6, lane = threadIdx.x & 63;
    int row = blockIdx.x * 4 + wave;
    float4 wv = *(const float4*)(Wh + (size_t)row * FD + lane * 4);
    float4 a0 = *(const float4*)(a_w + lane * 4);
    float4 a1 = *(const float4*)(a_w + FD + lane * 4);
    float d0 = wv.x * a0.x + wv.y * a0.y + wv.z * a0.z + wv.w * a0.w;
    float d1 = wv.x * a1.x + wv.y * a1.y + wv.z * a1.z + wv.w * a1.w;
#pragma unroll
    for (int off = 32; off; off >>= 1) {
        d0 += __shfl_down(d0, off, 64);
        d1 += __shfl_down(d1, off, 64);
    }
    if (lane == 0) { s_src[row] = d0; s_dst[row] = d1; }
}

// ---------------- K4: den_part[isp][b][j] = partial column sums ----------------
// grid 1024: b = blk&7, jhalf = (blk>>3)&1, isp = blk>>4; 32 i x 1024 j per block
__global__ __launch_bounds__(256) void k4_den(const float* __restrict__ A,
                                              const float* __restrict__ s_src,
                                              const float* __restrict__ s_dst,
                                              const float* __restrict__ a_bp,
                                              float* __restrict__ den_part) {
    const int blk = blockIdx.x;
    const int b = blk & 7;
    const int jhalf = (blk >> 3) & 1;
    const int isp = blk >> 4;
    const int i0 = isp * 32;
    const int j = jhalf * 1024 + threadIdx.x * 4;
    __shared__ float ss[32];
    if (threadIdx.x < 32) ss[threadIdx.x] = s_src[b * NN + i0 + threadIdx.x] + a_bp[0];
    __syncthreads();
    float4 sd = *(const float4*)(s_dst + b * NN + j);
    float ax = 0.f, ay = 0.f, az = 0.f, aw = 0.f;
    const float* Ap = A + ((size_t)b * NN + i0) * NN + j;
#pragma unroll 8
    for (int i = 0; i < 32; ++i) {
        float4 a = *(const float4*)(Ap + (size_t)i * NN);
        float si = ss[i];
        float e0 = si + sd.x; e0 = e0 > 0.f ? e0 : NEG_SLOPE * e0;
        float e1 = si + sd.y; e1 = e1 > 0.f ? e1 : NEG_SLOPE * e1;
        float e2 = si + sd.z; e2 = e2 > 0.f ? e2 : NEG_SLOPE * e2;
        float e3 = si + sd.w; e3 = e3 > 0.f ? e3 : NEG_SLOPE * e3;
        ax += a.x * __expf(e0);
        ay += a.y * __expf(e1);
        az += a.z * __expf(e2);
        aw += a.w * __expf(e3);
    }
    float4 r = (float4){ax, ay, az, aw};
    *(float4*)(den_part + (size_t)isp * (BB * NN) + b * NN + j) = r;
}

// ---------------- K5: WhT[b][o][j] = bf16( Wh[b][j][o] / (sum(den_part)+eps) ) ----
__global__ __launch_bounds__(256) void k5_wht(const float* __restrict__ Wh,
                                              const float* __restrict__ den_part,
                                              __bf16* __restrict__ WhT) {
    const int b = blockIdx.z;
    const int j0 = blockIdx.x * 64;
    const int o0 = blockIdx.y * 64;
    __shared__ float tile[64][65];
    __shared__ float invd[64];
    if (threadIdx.x < 64) {
        float s = 0.f;
        const float* dp = den_part + b * NN + j0 + threadIdx.x;
#pragma unroll 8
        for (int sI = 0; sI < 64; ++sI) s += dp[(size_t)sI * (BB * NN)];
        invd[threadIdx.x] = 1.f / (s + EPSV);
    }
    __syncthreads();
    int jr = threadIdx.x >> 4, oc = (threadIdx.x & 15) * 4;
#pragma unroll
    for (int p = 0; p < 4; ++p) {
        int jj = jr + p * 16;
        float4 v = *(const float4*)(Wh + (size_t)(b * NN + j0 + jj) * FD + o0 + oc);
        float s = invd[jj];
        tile[jj][oc + 0] = v.x * s;
        tile[jj][oc + 1] = v.y * s;
        tile[jj][oc + 2] = v.z * s;
        tile[jj][oc + 3] = v.w * s;
    }
    __syncthreads();
    int ow = threadIdx.x >> 4, jc = (threadIdx.x & 15) * 4;
#pragma unroll
    for (int p = 0; p < 4; ++p) {
        int o = ow + p * 16;
        bf16x4 wv;
        wv[0] = (__bf16)tile[jc + 0][o];
        wv[1] = (__bf16)tile[jc + 1][o];
        wv[2] = (__bf16)tile[jc + 2][o];
        wv[3] = (__bf16)tile[jc + 3][o];
        *(bf16x4*)(WhT + (size_t)(b * FD + o0 + o) * NN + j0 + jc) = wv;
    }
}

// ---------------- K6: barrier-free fused GEMM: out = (A*exp(lrelu(e))) @ WhT^T ----
// grid 1024: b = blk&7 (XCD affinity), r_ = blk>>3: rowtile = r_&31 (64 rows),
// otile = r_>>5 (0..3, 64 cols). 256 thr = 4 waves; wave w: rows i0+w*16..+15,
// cols otile*64..+63. Full K=2048, no LDS, no barriers, no partials.
// A-frags from global + inline exp; B-frags = 16-line L2 gathers of WhT.
__global__ __launch_bounds__(256) void k6_out(const float* __restrict__ A,
                                              const __bf16* __restrict__ WhT,
                                              const float* __restrict__ s_src,
                                              const float* __restrict__ s_dst,
                                              const float* __restrict__ a_bp,
                                              float* __restrict__ out) {
    const int blk = blockIdx.x;
    const int b = blk & 7;
    const int r_ = blk >> 3;
    const int rowtile = r_ & 31;
    const int otile = r_ >> 5;
    const int i0 = rowtile * 64;
    const int o0 = otile * 64;
    const int t = threadIdx.x;
    const int w = t >> 6, lane = t & 63;
    const int m = lane & 15, quad = lane >> 4;

    const int row = i0 + w * 16 + m;
    const float ssr = s_src[b * NN + row] + a_bp[0];
    const float* Arow = A + ((size_t)b * NN + row) * NN + quad * 8;
    const float* sdp = s_dst + b * NN + quad * 8;
    const __bf16* Bb = WhT + (size_t)(b * FD + o0 + m) * NN + quad * 8;

    f32x4 acc[4];
#pragma unroll
    for (int n = 0; n < 4; ++n) acc[n] = (f32x4){0.f, 0.f, 0.f, 0.f};

    // register prefetch of A/sd for step 0
    float4 a0 = *(const float4*)(Arow);
    float4 a1 = *(const float4*)(Arow + 4);
    float4 s0 = *(const float4*)(sdp);
    float4 s1 = *(const float4*)(sdp + 4);

    for (int kk = 0; kk < 64; ++kk) {
        // issue all 4 B-frag loads first: their L2 latency hides under exp VALU work
        bf16x8 bf0 = *(const bf16x8*)(Bb + (size_t)(0 * 16) * NN + kk * 32);
        bf16x8 bf1 = *(const bf16x8*)(Bb + (size_t)(1 * 16) * NN + kk * 32);
        bf16x8 bf2 = *(const bf16x8*)(Bb + (size_t)(2 * 16) * NN + kk * 32);
        bf16x8 bf3 = *(const bf16x8*)(Bb + (size_t)(3 * 16) * NN + kk * 32);
        float4 ca0 = a0, ca1 = a1, cs0 = s0, cs1 = s1;
        if (kk < 63) {   // prefetch next A/sd
            const float* An = Arow + (kk + 1) * 32;
            const float* Sn = sdp + (kk + 1) * 32;
            a0 = *(const float4*)(An);
            a1 = *(const float4*)(An + 4);
            s0 = *(const float4*)(Sn);
            s1 = *(const float4*)(Sn + 4);
        }
        bf16x8 af;
        float e;
        e = ssr + cs0.x; e = e > 0.f ? e : NEG_SLOPE * e; af[0] = (__bf16)(ca0.x * __expf(e));
        e = ssr + cs0.y; e = e > 0.f ? e : NEG_SLOPE * e; af[1] = (__bf16)(ca0.y * __expf(e));
        e = ssr + cs0.z; e = e > 0.f ? e : NEG_SLOPE * e; af[2] = (__bf16)(ca0.z * __expf(e));
        e = ssr + cs0.w; e = e > 0.f ? e : NEG_SLOPE * e; af[3] = (__bf16)(ca0.w * __expf(e));
        e = ssr + cs1.x; e = e > 0.f ? e : NEG_SLOPE * e; af[4] = (__bf16)(ca1.x * __expf(e));
        e = ssr + cs1.y; e = e > 0.f ? e : NEG_SLOPE * e; af[5] = (__bf16)(ca1.y * __expf(e));
        e = ssr + cs1.z; e = e > 0.f ? e : NEG_SLOPE * e; af[6] = (__bf16)(ca1.z * __expf(e));
        e = ssr + cs1.w; e = e > 0.f ? e : NEG_SLOPE * e; af[7] = (__bf16)(ca1.w * __expf(e));
        acc[0] = __builtin_amdgcn_mfma_f32_16x16x32_bf16(af, bf0, acc[0], 0, 0, 0);
        acc[1] = __builtin_amdgcn_mfma_f32_16x16x32_bf16(af, bf1, acc[1], 0, 0, 0);
        acc[2] = __builtin_amdgcn_mfma_f32_16x16x32_bf16(af, bf2, acc[2], 0, 0, 0);
        acc[3] = __builtin_amdgcn_mfma_f32_16x16x32_bf16(af, bf3, acc[3], 0, 0, 0);
    }

#pragma unroll
    for (int n = 0; n < 4; ++n) {
        int o = o0 + n * 16 + m;
#pragma unroll
        for (int rr = 0; rr < 4; ++rr) {
            int orow = i0 + w * 16 + quad * 4 + rr;
            out[((size_t)b * NN + orow) * FD + o] = acc[n][rr];
        }
    }
}

extern "C" void kernel_launch(void* const* d_in, const int* in_sizes, int n_in,
                              void* d_out, int out_size, void* d_ws, size_t ws_size,
                              hipStream_t stream) {
    const float* A   = (const float*)d_in[0];
    const float* x   = (const float*)d_in[1];
    const float* W   = (const float*)d_in[2];
    const float* a_w = (const float*)d_in[3];
    const float* a_b = (const float*)d_in[4];
    float* out = (float*)d_out;

    char* ws = (char*)d_ws;
    __bf16* WT      = (__bf16*)ws;                      // 131,072 B
    float*  Wh      = (float*)(ws + 131072);            // 16,777,216 B
    __bf16* WhT     = (__bf16*)(ws + 16908288);         // 8,388,608 B
    float*  s_src   = (float*)(ws + 25296896);          // 65,536 B
    float*  s_dst   = (float*)(ws + 25362432);          // 65,536 B
    float*  den_part= (float*)(ws + 25427968);          // 64*16384*4 = 4,194,304 B
                                                        // total = 29,622,272 B

    k1_prep<<<256, 256, 0, stream>>>(W, WT);
    k2_whgemm<<<512, 256, 0, stream>>>(x, WT, Wh);
    k3_scores<<<4096, 256, 0, stream>>>(Wh, a_w, s_src, s_dst);
    k4_den<<<1024, 256, 0, stream>>>(A, s_src, s_dst, a_b, den_part);
    k5_wht<<<dim3(32, 4, 8), 256, 0, stream>>>(Wh, den_part, WhT);
    k6_out<<<1024, 256, 0, stream>>>(A, WhT, s_src, s_dst, a_b, out);
}

// Round 7
// 303.599 us; speedup vs baseline: 1.4035x; 1.4035x over previous
//
#include <hip/hip_runtime.h>
#include <hip/hip_bf16.h>

#define NN 2048
#define BB 8
#define FD 256
#define NEG_SLOPE 0.2f
#define EPSV 1e-7f
#define PSTR 36   // padded P row stride (bf16)

typedef __bf16 bf16x8 __attribute__((ext_vector_type(8)));
typedef __bf16 bf16x4 __attribute__((ext_vector_type(4)));
typedef __bf16 bf16x2 __attribute__((ext_vector_type(2)));
typedef float f32x4 __attribute__((ext_vector_type(4)));

// async 16B global -> LDS (lds base wave-uniform; dest = base + lane*16)
__device__ __forceinline__ void gload16(const __bf16* g, __bf16* l) {
    __builtin_amdgcn_global_load_lds((const __attribute__((address_space(1))) unsigned int*)g,
                                     (__attribute__((address_space(3))) unsigned int*)l,
                                     16, 0, 0);
}

// ---------------- K1: WT[o][f] = bf16(W[f][o]) ----------------
__global__ __launch_bounds__(256) void k1_prep(const float* __restrict__ W,
                                               __bf16* __restrict__ WT) {
    int idx = blockIdx.x * 256 + threadIdx.x;   // 256 blocks
    int o = idx >> 8, f = idx & 255;
    WT[idx] = (__bf16)W[f * FD + o];
}

// ---------------- K2: Wh = x @ W (bf16 MFMA) + fused s_src/s_dst scores --------
// 512 blocks x 32 rows. Wave = 16 rows x 128 cols (2 rowpairs x 2 ohalves).
__global__ __launch_bounds__(256) void k2_whgemm(const float* __restrict__ x,
                                                 const __bf16* __restrict__ WT,
                                                 const float* __restrict__ a_w,
                                                 float* __restrict__ Wh,
                                                 float* __restrict__ s_src,
                                                 float* __restrict__ s_dst) {
    const int wave = threadIdx.x >> 6;
    const int lane = threadIdx.x & 63;
    const int row0 = blockIdx.x * 32 + (wave >> 1) * 16;
    const int ohalf = (wave & 1) * 128;
    const int m = lane & 15;
    const int quad = lane >> 4;
    const int row = row0 + m;
    const float* xrow = x + (size_t)row * FD + quad * 8;

    f32x4 acc[8];
#pragma unroll
    for (int n = 0; n < 8; ++n) acc[n] = (f32x4){0.f, 0.f, 0.f, 0.f};

    for (int k0 = 0; k0 < FD; k0 += 32) {
        float4 xa = *(const float4*)(xrow + k0);
        float4 xb = *(const float4*)(xrow + k0 + 4);
        bf16x8 af;
        af[0] = (__bf16)xa.x; af[1] = (__bf16)xa.y; af[2] = (__bf16)xa.z; af[3] = (__bf16)xa.w;
        af[4] = (__bf16)xb.x; af[5] = (__bf16)xb.y; af[6] = (__bf16)xb.z; af[7] = (__bf16)xb.w;
#pragma unroll
        for (int n = 0; n < 8; ++n) {
            int o = ohalf + n * 16 + m;
            bf16x8 bf = *(const bf16x8*)(WT + o * FD + k0 + quad * 8);
            acc[n] = __builtin_amdgcn_mfma_f32_16x16x32_bf16(af, bf, acc[n], 0, 0, 0);
        }
    }
#pragma unroll
    for (int n = 0; n < 8; ++n) {
        int o = ohalf + n * 16 + m;
#pragma unroll
        for (int r = 0; r < 4; ++r) {
            Wh[(size_t)(row0 + quad * 4 + r) * FD + o] = acc[n][r];
        }
    }

    // fused scores: psrc[r] = sum_n acc[n][r]*a_w[o], reduce over m lanes
    float psrc[4] = {0.f, 0.f, 0.f, 0.f};
    float pdst[4] = {0.f, 0.f, 0.f, 0.f};
#pragma unroll
    for (int n = 0; n < 8; ++n) {
        int o = ohalf + n * 16 + m;
        float awS = a_w[o], awD = a_w[FD + o];
#pragma unroll
        for (int r = 0; r < 4; ++r) {
            psrc[r] += acc[n][r] * awS;
            pdst[r] += acc[n][r] * awD;
        }
    }
#pragma unroll
    for (int off = 1; off <= 8; off <<= 1) {
#pragma unroll
        for (int r = 0; r < 4; ++r) {
            psrc[r] += __shfl_xor(psrc[r], off, 64);
            pdst[r] += __shfl_xor(pdst[r], off, 64);
        }
    }
    __shared__ float sS[2][2][16], sD[2][2][16];
    if (m == 0) {
        int rp = wave >> 1, oh = wave & 1;
#pragma unroll
        for (int r = 0; r < 4; ++r) {
            sS[rp][oh][quad * 4 + r] = psrc[r];
            sD[rp][oh][quad * 4 + r] = pdst[r];
        }
    }
    __syncthreads();
    if (threadIdx.x < 32) {
        int rp = threadIdx.x >> 4, idx = threadIdx.x & 15;
        int orow = blockIdx.x * 32 + rp * 16 + idx;
        s_src[orow] = sS[rp][0][idx] + sS[rp][1][idx];
        s_dst[orow] = sD[rp][0][idx] + sD[rp][1][idx];
    }
}

// ---------------- K4: den_part[isp][b][j] = partial column sums ----------------
// grid 1024: b = blk&7, jhalf = (blk>>3)&1, isp = blk>>4; 32 i x 1024 j per block
__global__ __launch_bounds__(256) void k4_den(const float* __restrict__ A,
                                              const float* __restrict__ s_src,
                                              const float* __restrict__ s_dst,
                                              const float* __restrict__ a_bp,
                                              float* __restrict__ den_part) {
    const int blk = blockIdx.x;
    const int b = blk & 7;
    const int jhalf = (blk >> 3) & 1;
    const int isp = blk >> 4;
    const int i0 = isp * 32;
    const int j = jhalf * 1024 + threadIdx.x * 4;
    __shared__ float ss[32];
    if (threadIdx.x < 32) ss[threadIdx.x] = s_src[b * NN + i0 + threadIdx.x] + a_bp[0];
    __syncthreads();
    float4 sd = *(const float4*)(s_dst + b * NN + j);
    float ax = 0.f, ay = 0.f, az = 0.f, aw = 0.f;
    const float* Ap = A + ((size_t)b * NN + i0) * NN + j;
#pragma unroll 8
    for (int i = 0; i < 32; ++i) {
        float4 a = *(const float4*)(Ap + (size_t)i * NN);
        float si = ss[i];
        float e0 = si + sd.x; e0 = e0 > 0.f ? e0 : NEG_SLOPE * e0;
        float e1 = si + sd.y; e1 = e1 > 0.f ? e1 : NEG_SLOPE * e1;
        float e2 = si + sd.z; e2 = e2 > 0.f ? e2 : NEG_SLOPE * e2;
        float e3 = si + sd.w; e3 = e3 > 0.f ? e3 : NEG_SLOPE * e3;
        ax += a.x * __expf(e0);
        ay += a.y * __expf(e1);
        az += a.z * __expf(e2);
        aw += a.w * __expf(e3);
    }
    float4 r = (float4){ax, ay, az, aw};
    *(float4*)(den_part + (size_t)isp * (BB * NN) + b * NN + j) = r;
}

// ---------------- K5: WhT[b][o][j] = bf16( Wh[b][j][o] / (sum(den_part)+eps) ) ----
__global__ __launch_bounds__(256) void k5_wht(const float* __restrict__ Wh,
                                              const float* __restrict__ den_part,
                                              __bf16* __restrict__ WhT) {
    const int b = blockIdx.z;
    const int j0 = blockIdx.x * 64;
    const int o0 = blockIdx.y * 64;
    __shared__ float tile[64][65];
    __shared__ float invd[64];
    if (threadIdx.x < 64) {
        float s = 0.f;
        const float* dp = den_part + b * NN + j0 + threadIdx.x;
#pragma unroll 8
        for (int sI = 0; sI < 64; ++sI) s += dp[(size_t)sI * (BB * NN)];
        invd[threadIdx.x] = 1.f / (s + EPSV);
    }
    __syncthreads();
    int jr = threadIdx.x >> 4, oc = (threadIdx.x & 15) * 4;
#pragma unroll
    for (int p = 0; p < 4; ++p) {
        int jj = jr + p * 16;
        float4 v = *(const float4*)(Wh + (size_t)(b * NN + j0 + jj) * FD + o0 + oc);
        float s = invd[jj];
        tile[jj][oc + 0] = v.x * s;
        tile[jj][oc + 1] = v.y * s;
        tile[jj][oc + 2] = v.z * s;
        tile[jj][oc + 3] = v.w * s;
    }
    __syncthreads();
    int ow = threadIdx.x >> 4, jc = (threadIdx.x & 15) * 4;
#pragma unroll
    for (int p = 0; p < 4; ++p) {
        int o = ow + p * 16;
        bf16x4 wv;
        wv[0] = (__bf16)tile[jc + 0][o];
        wv[1] = (__bf16)tile[jc + 1][o];
        wv[2] = (__bf16)tile[jc + 2][o];
        wv[3] = (__bf16)tile[jc + 3][o];
        *(bf16x4*)(WhT + (size_t)(b * FD + o0 + o) * NN + j0 + jc) = wv;
    }
}

// ---------------- K6: fused full-K GEMM: out = (A*exp(lrelu(e))) @ WhT^T ---------
// grid 512: b = blk&7 (XCD affinity), itile = blk>>3 (0..63). Block = 32i x 256o,
// full K=2048, A read once. 512 threads = 8 waves (2 wrow x 4 wcol); wave = 16i x 64o.
// P (32x32) built inline into dbuf LDS; B (256x32) via async global_load_lds dbuf.
// 16 waves/CU (vs R5's 8) to hide the per-step barrier drain.
__global__ __launch_bounds__(512) void k6_out(const float* __restrict__ A,
                                              const __bf16* __restrict__ WhT,
                                              const float* __restrict__ s_src,
                                              const float* __restrict__ s_dst,
                                              const float* __restrict__ a_bp,
                                              float* __restrict__ out) {
    __shared__ __bf16 Pt[2][32 * PSTR];   // 2 x 2304 B
    __shared__ __bf16 Bt[2][256 * 32];    // 2 x 16 KiB
    const int blk = blockIdx.x;
    const int b = blk & 7;
    const int itile = blk >> 3;
    const int i0 = itile * 32;
    const int t = threadIdx.x;
    const int w = t >> 6, lane = t & 63;
    const int m = lane & 15, quad = lane >> 4;
    const int wrow = w >> 2, wcol = w & 3;

    // P-build role: thread t -> row t>>4 (0..31), cols (t&15)*2 .. +1
    const int prow = t >> 4, pjc = (t & 15) * 2;
    const float ssr = s_src[b * NN + i0 + prow] + a_bp[0];
    const float* Abase = A + ((size_t)(b * NN + i0 + prow)) * NN + pjc;
    const float* sdbase = s_dst + b * NN + pjc;
    __bf16* Pw = &Pt[0][0] + prow * PSTR + pjc;
    const int pstep = 32 * PSTR;

    // B staging: thread t -> row t>>2 (0..127), chunk t&3; two calls cover 256 rows
    const int srow = t >> 2, schunk = t & 3;
    const __bf16* gB = WhT + ((size_t)(b * FD + srow)) * NN + schunk * 8;
    __bf16* lB = &Bt[0][0] + (w * 16) * 32;   // wave-uniform
    const int lstepB = 256 * 32;

    // prefetch A/sd regs for step 0; stage B step 0 into buf 0
    float2 a0 = *(const float2*)(Abase);
    float2 q0 = *(const float2*)(sdbase);
    gload16(gB, lB);
    gload16(gB + (size_t)128 * NN, lB + 128 * 32);

#define BUILD_P(dstbuf)                                                          \
    {                                                                            \
        bf16x2 pv; float e;                                                      \
        e = ssr + q0.x; e = e > 0.f ? e : NEG_SLOPE * e; pv[0] = (__bf16)(a0.x * __expf(e)); \
        e = ssr + q0.y; e = e > 0.f ? e : NEG_SLOPE * e; pv[1] = (__bf16)(a0.y * __expf(e)); \
        *(bf16x2*)(Pw + (dstbuf) * pstep) = pv;                                  \
    }

    BUILD_P(0)

    f32x4 acc[4];
#pragma unroll
    for (int n = 0; n < 4; ++n) acc[n] = (f32x4){0.f, 0.f, 0.f, 0.f};

    const __bf16* Pr = &Pt[0][0] + (wrow * 16 + m) * PSTR + quad * 8;
    const __bf16* Br = &Bt[0][0] + (wcol * 64 + m) * 32 + quad * 8;

    for (int kk = 0; kk < 64; ++kk) {
        __syncthreads();   // buf (kk&1) fully staged
        const int cur = kk & 1, nb = cur ^ 1;
        if (kk < 63) {
            gload16(gB + (kk + 1) * 32, lB + nb * lstepB);
            gload16(gB + (size_t)128 * NN + (kk + 1) * 32, lB + nb * lstepB + 128 * 32);
            a0 = *(const float2*)(Abase + (kk + 1) * 32);
            q0 = *(const float2*)(sdbase + (kk + 1) * 32);
        }
        const __bf16* Pk = Pr + cur * pstep;
        const __bf16* Bk = Br + cur * lstepB;
        bf16x8 af = *(const bf16x8*)(Pk);
#pragma unroll
        for (int n = 0; n < 4; ++n) {
            bf16x8 bfr = *(const bf16x8*)(Bk + n * 16 * 32);
            acc[n] = __builtin_amdgcn_mfma_f32_16x16x32_bf16(af, bfr, acc[n], 0, 0, 0);
        }
        if (kk < 63) BUILD_P(nb)
    }

#pragma unroll
    for (int n = 0; n < 4; ++n) {
        int o = wcol * 64 + n * 16 + m;
#pragma unroll
        for (int rr = 0; rr < 4; ++rr) {
            int orow = i0 + wrow * 16 + quad * 4 + rr;
            out[((size_t)b * NN + orow) * FD + o] = acc[n][rr];
        }
    }
#undef BUILD_P
}

extern "C" void kernel_launch(void* const* d_in, const int* in_sizes, int n_in,
                              void* d_out, int out_size, void* d_ws, size_t ws_size,
                              hipStream_t stream) {
    const float* A   = (const float*)d_in[0];
    const float* x   = (const float*)d_in[1];
    const float* W   = (const float*)d_in[2];
    const float* a_w = (const float*)d_in[3];
    const float* a_b = (const float*)d_in[4];
    float* out = (float*)d_out;

    char* ws = (char*)d_ws;
    __bf16* WT      = (__bf16*)ws;                      // 131,072 B
    float*  Wh      = (float*)(ws + 131072);            // 16,777,216 B
    __bf16* WhT     = (__bf16*)(ws + 16908288);         // 8,388,608 B
    float*  s_src   = (float*)(ws + 25296896);          // 65,536 B
    float*  s_dst   = (float*)(ws + 25362432);          // 65,536 B
    float*  den_part= (float*)(ws + 25427968);          // 64*16384*4 = 4,194,304 B

    k1_prep<<<256, 256, 0, stream>>>(W, WT);
    k2_whgemm<<<512, 256, 0, stream>>>(x, WT, a_w, Wh, s_src, s_dst);
    k4_den<<<1024, 256, 0, stream>>>(A, s_src, s_dst, a_b, den_part);
    k5_wht<<<dim3(32, 4, 8), 256, 0, stream>>>(Wh, den_part, WhT);
    k6_out<<<512, 512, 0, stream>>>(A, WhT, s_src, s_dst, a_b, out);
}

// Round 8
// 297.968 us; speedup vs baseline: 1.4300x; 1.0189x over previous
//
#include <hip/hip_runtime.h>
#include <hip/hip_bf16.h>

#define NN 2048
#define BB 8
#define FD 256
#define NEG_SLOPE 0.2f
#define EPSV 1e-7f
#define PSTR 36   // padded P row stride (bf16)

typedef __bf16 bf16x8 __attribute__((ext_vector_type(8)));
typedef __bf16 bf16x4 __attribute__((ext_vector_type(4)));
typedef float f32x4 __attribute__((ext_vector_type(4)));

// async 16B global -> LDS (lds base wave-uniform; dest = base + lane*16)
__device__ __forceinline__ void gload16(const __bf16* g, __bf16* l) {
    __builtin_amdgcn_global_load_lds((const __attribute__((address_space(1))) unsigned int*)g,
                                     (__attribute__((address_space(3))) unsigned int*)l,
                                     16, 0, 0);
}

// ---------------- K1: WT[o][f] = bf16(W[f][o]) ----------------
__global__ __launch_bounds__(256) void k1_prep(const float* __restrict__ W,
                                               __bf16* __restrict__ WT) {
    int idx = blockIdx.x * 256 + threadIdx.x;   // 256 blocks
    int o = idx >> 8, f = idx & 255;
    WT[idx] = (__bf16)W[f * FD + o];
}

// ---------------- K2: Wh = x @ W (bf16 MFMA) + fused s_src/s_dst scores --------
__global__ __launch_bounds__(256) void k2_whgemm(const float* __restrict__ x,
                                                 const __bf16* __restrict__ WT,
                                                 const float* __restrict__ a_w,
                                                 float* __restrict__ Wh,
                                                 float* __restrict__ s_src,
                                                 float* __restrict__ s_dst) {
    const int wave = threadIdx.x >> 6;
    const int lane = threadIdx.x & 63;
    const int row0 = blockIdx.x * 32 + (wave >> 1) * 16;
    const int ohalf = (wave & 1) * 128;
    const int m = lane & 15;
    const int quad = lane >> 4;
    const int row = row0 + m;
    const float* xrow = x + (size_t)row * FD + quad * 8;

    f32x4 acc[8];
#pragma unroll
    for (int n = 0; n < 8; ++n) acc[n] = (f32x4){0.f, 0.f, 0.f, 0.f};

    for (int k0 = 0; k0 < FD; k0 += 32) {
        float4 xa = *(const float4*)(xrow + k0);
        float4 xb = *(const float4*)(xrow + k0 + 4);
        bf16x8 af;
        af[0] = (__bf16)xa.x; af[1] = (__bf16)xa.y; af[2] = (__bf16)xa.z; af[3] = (__bf16)xa.w;
        af[4] = (__bf16)xb.x; af[5] = (__bf16)xb.y; af[6] = (__bf16)xb.z; af[7] = (__bf16)xb.w;
#pragma unroll
        for (int n = 0; n < 8; ++n) {
            int o = ohalf + n * 16 + m;
            bf16x8 bf = *(const bf16x8*)(WT + o * FD + k0 + quad * 8);
            acc[n] = __builtin_amdgcn_mfma_f32_16x16x32_bf16(af, bf, acc[n], 0, 0, 0);
        }
    }
#pragma unroll
    for (int n = 0; n < 8; ++n) {
        int o = ohalf + n * 16 + m;
#pragma unroll
        for (int r = 0; r < 4; ++r) {
            Wh[(size_t)(row0 + quad * 4 + r) * FD + o] = acc[n][r];
        }
    }

    float psrc[4] = {0.f, 0.f, 0.f, 0.f};
    float pdst[4] = {0.f, 0.f, 0.f, 0.f};
#pragma unroll
    for (int n = 0; n < 8; ++n) {
        int o = ohalf + n * 16 + m;
        float awS = a_w[o], awD = a_w[FD + o];
#pragma unroll
        for (int r = 0; r < 4; ++r) {
            psrc[r] += acc[n][r] * awS;
            pdst[r] += acc[n][r] * awD;
        }
    }
#pragma unroll
    for (int off = 1; off <= 8; off <<= 1) {
#pragma unroll
        for (int r = 0; r < 4; ++r) {
            psrc[r] += __shfl_xor(psrc[r], off, 64);
            pdst[r] += __shfl_xor(pdst[r], off, 64);
        }
    }
    __shared__ float sS[2][2][16], sD[2][2][16];
    if (m == 0) {
        int rp = wave >> 1, oh = wave & 1;
#pragma unroll
        for (int r = 0; r < 4; ++r) {
            sS[rp][oh][quad * 4 + r] = psrc[r];
            sD[rp][oh][quad * 4 + r] = pdst[r];
        }
    }
    __syncthreads();
    if (threadIdx.x < 32) {
        int rp = threadIdx.x >> 4, idx = threadIdx.x & 15;
        int orow = blockIdx.x * 32 + rp * 16 + idx;
        s_src[orow] = sS[rp][0][idx] + sS[rp][1][idx];
        s_dst[orow] = sD[rp][0][idx] + sD[rp][1][idx];
    }
}

// ---------------- K4: den_part[isp][b][j] = partial column sums ----------------
__global__ __launch_bounds__(256) void k4_den(const float* __restrict__ A,
                                              const float* __restrict__ s_src,
                                              const float* __restrict__ s_dst,
                                              const float* __restrict__ a_bp,
                                              float* __restrict__ den_part) {
    const int blk = blockIdx.x;
    const int b = blk & 7;
    const int jhalf = (blk >> 3) & 1;
    const int isp = blk >> 4;
    const int i0 = isp * 32;
    const int j = jhalf * 1024 + threadIdx.x * 4;
    __shared__ float ss[32];
    if (threadIdx.x < 32) ss[threadIdx.x] = s_src[b * NN + i0 + threadIdx.x] + a_bp[0];
    __syncthreads();
    float4 sd = *(const float4*)(s_dst + b * NN + j);
    float ax = 0.f, ay = 0.f, az = 0.f, aw = 0.f;
    const float* Ap = A + ((size_t)b * NN + i0) * NN + j;
#pragma unroll 8
    for (int i = 0; i < 32; ++i) {
        float4 a = *(const float4*)(Ap + (size_t)i * NN);
        float si = ss[i];
        float e0 = si + sd.x; e0 = e0 > 0.f ? e0 : NEG_SLOPE * e0;
        float e1 = si + sd.y; e1 = e1 > 0.f ? e1 : NEG_SLOPE * e1;
        float e2 = si + sd.z; e2 = e2 > 0.f ? e2 : NEG_SLOPE * e2;
        float e3 = si + sd.w; e3 = e3 > 0.f ? e3 : NEG_SLOPE * e3;
        ax += a.x * __expf(e0);
        ay += a.y * __expf(e1);
        az += a.z * __expf(e2);
        aw += a.w * __expf(e3);
    }
    float4 r = (float4){ax, ay, az, aw};
    *(float4*)(den_part + (size_t)isp * (BB * NN) + b * NN + j) = r;
}

// ---------------- K5: WhT[b][o][j] = bf16( Wh[b][j][o] / (sum(den_part)+eps) ) ----
__global__ __launch_bounds__(256) void k5_wht(const float* __restrict__ Wh,
                                              const float* __restrict__ den_part,
                                              __bf16* __restrict__ WhT) {
    const int b = blockIdx.z;
    const int j0 = blockIdx.x * 64;
    const int o0 = blockIdx.y * 64;
    __shared__ float tile[64][65];
    __shared__ float invd[64];
    if (threadIdx.x < 64) {
        float s = 0.f;
        const float* dp = den_part + b * NN + j0 + threadIdx.x;
#pragma unroll 8
        for (int sI = 0; sI < 64; ++sI) s += dp[(size_t)sI * (BB * NN)];
        invd[threadIdx.x] = 1.f / (s + EPSV);
    }
    __syncthreads();
    int jr = threadIdx.x >> 4, oc = (threadIdx.x & 15) * 4;
#pragma unroll
    for (int p = 0; p < 4; ++p) {
        int jj = jr + p * 16;
        float4 v = *(const float4*)(Wh + (size_t)(b * NN + j0 + jj) * FD + o0 + oc);
        float s = invd[jj];
        tile[jj][oc + 0] = v.x * s;
        tile[jj][oc + 1] = v.y * s;
        tile[jj][oc + 2] = v.z * s;
        tile[jj][oc + 3] = v.w * s;
    }
    __syncthreads();
    int ow = threadIdx.x >> 4, jc = (threadIdx.x & 15) * 4;
#pragma unroll
    for (int p = 0; p < 4; ++p) {
        int o = ow + p * 16;
        bf16x4 wv;
        wv[0] = (__bf16)tile[jc + 0][o];
        wv[1] = (__bf16)tile[jc + 1][o];
        wv[2] = (__bf16)tile[jc + 2][o];
        wv[3] = (__bf16)tile[jc + 3][o];
        *(bf16x4*)(WhT + (size_t)(b * FD + o0 + o) * NN + j0 + jc) = wv;
    }
}

// ---------------- K6: fused full-K GEMM: out = (A*exp(lrelu(e))) @ WhT^T ---------
// grid 1024: b = blk&7 (XCD affinity), r_ = blk>>3: itile = r_&63, oh = r_>>6.
// Block = 32i x 128o, 256 threads = 4 waves (2 wrow x 2 wcol); wave = 16i x 64o.
// 4 blocks/CU -> 4 independent barrier groups; both o-halves of an itile live on
// the same XCD so the second A read hits that XCD's L2 (HBM A traffic ~1x).
__global__ __launch_bounds__(256) void k6_out(const float* __restrict__ A,
                                              const __bf16* __restrict__ WhT,
                                              const float* __restrict__ s_src,
                                              const float* __restrict__ s_dst,
                                              const float* __restrict__ a_bp,
                                              float* __restrict__ out) {
    __shared__ __bf16 Pt[2][32 * PSTR];   // 2 x 2304 B
    __shared__ __bf16 Bt[2][128 * 32];    // 2 x 8 KiB
    const int blk = blockIdx.x;
    const int b = blk & 7;
    const int r_ = blk >> 3;
    const int itile = r_ & 63;
    const int oh = r_ >> 6;
    const int i0 = itile * 32;
    const int o0 = oh * 128;
    const int t = threadIdx.x;
    const int w = t >> 6, lane = t & 63;
    const int m = lane & 15, quad = lane >> 4;
    const int wrow = w >> 1, wcol = w & 1;

    // P-build role: thread t -> row t>>3 (0..31), cols (t&7)*4 .. +3
    const int prow = t >> 3, pj = (t & 7) * 4;
    const float ssr = s_src[b * NN + i0 + prow] + a_bp[0];
    const float* Abase = A + ((size_t)(b * NN + i0 + prow)) * NN + pj;
    const float* sdbase = s_dst + b * NN + pj;
    __bf16* Pw = &Pt[0][0] + prow * PSTR + pj;
    const int pstep = 32 * PSTR;

    // B staging: wave w call c stages B-rows [w*16 + c*64, +16); lane ℓ -> row +(ℓ>>2),
    // 16B chunk ℓ&3. Covers 128 rows x 32 K per step.
    const __bf16* gB0 = WhT + ((size_t)(b * FD + o0 + w * 16 + (lane >> 2))) * NN + (lane & 3) * 8;
    const __bf16* gB1 = gB0 + (size_t)64 * NN;
    __bf16* lB0 = &Bt[0][0] + (w * 16) * 32;        // wave-uniform
    __bf16* lB1 = &Bt[0][0] + (w * 16 + 64) * 32;
    const int lstepB = 128 * 32;

    // prefetch A/sd regs for step 0; stage B step 0 into buf 0
    float4 a0 = *(const float4*)(Abase);
    float4 q0 = *(const float4*)(sdbase);
    gload16(gB0, lB0);
    gload16(gB1, lB1);

#define BUILD_P(dstbuf)                                                          \
    {                                                                            \
        bf16x4 pv; float e;                                                      \
        e = ssr + q0.x; e = e > 0.f ? e : NEG_SLOPE * e; pv[0] = (__bf16)(a0.x * __expf(e)); \
        e = ssr + q0.y; e = e > 0.f ? e : NEG_SLOPE * e; pv[1] = (__bf16)(a0.y * __expf(e)); \
        e = ssr + q0.z; e = e > 0.f ? e : NEG_SLOPE * e; pv[2] = (__bf16)(a0.z * __expf(e)); \
        e = ssr + q0.w; e = e > 0.f ? e : NEG_SLOPE * e; pv[3] = (__bf16)(a0.w * __expf(e)); \
        *(bf16x4*)(Pw + (dstbuf) * pstep) = pv;                                  \
    }

    BUILD_P(0)

    f32x4 acc[4];
#pragma unroll
    for (int n = 0; n < 4; ++n) acc[n] = (f32x4){0.f, 0.f, 0.f, 0.f};

    const __bf16* Pr = &Pt[0][0] + (wrow * 16 + m) * PSTR + quad * 8;
    const __bf16* Br = &Bt[0][0] + (wcol * 64 + m) * 32 + quad * 8;

    for (int kk = 0; kk < 64; ++kk) {
        __syncthreads();   // buf (kk&1) fully staged
        const int cur = kk & 1, nb = cur ^ 1;
        if (kk < 63) {
            gload16(gB0 + (kk + 1) * 32, lB0 + nb * lstepB);
            gload16(gB1 + (kk + 1) * 32, lB1 + nb * lstepB);
            a0 = *(const float4*)(Abase + (kk + 1) * 32);
            q0 = *(const float4*)(sdbase + (kk + 1) * 32);
        }
        const __bf16* Pk = Pr + cur * pstep;
        const __bf16* Bk = Br + cur * lstepB;
        bf16x8 af = *(const bf16x8*)(Pk);
#pragma unroll
        for (int n = 0; n < 4; ++n) {
            bf16x8 bfr = *(const bf16x8*)(Bk + n * 16 * 32);
            acc[n] = __builtin_amdgcn_mfma_f32_16x16x32_bf16(af, bfr, acc[n], 0, 0, 0);
        }
        if (kk < 63) BUILD_P(nb)
    }

#pragma unroll
    for (int n = 0; n < 4; ++n) {
        int o = o0 + wcol * 64 + n * 16 + m;
#pragma unroll
        for (int rr = 0; rr < 4; ++rr) {
            int orow = i0 + wrow * 16 + quad * 4 + rr;
            out[((size_t)b * NN + orow) * FD + o] = acc[n][rr];
        }
    }
#undef BUILD_P
}

extern "C" void kernel_launch(void* const* d_in, const int* in_sizes, int n_in,
                              void* d_out, int out_size, void* d_ws, size_t ws_size,
                              hipStream_t stream) {
    const float* A   = (const float*)d_in[0];
    const float* x   = (const float*)d_in[1];
    const float* W   = (const float*)d_in[2];
    const float* a_w = (const float*)d_in[3];
    const float* a_b = (const float*)d_in[4];
    float* out = (float*)d_out;

    char* ws = (char*)d_ws;
    __bf16* WT      = (__bf16*)ws;                      // 131,072 B
    float*  Wh      = (float*)(ws + 131072);            // 16,777,216 B
    __bf16* WhT     = (__bf16*)(ws + 16908288);         // 8,388,608 B
    float*  s_src   = (float*)(ws + 25296896);          // 65,536 B
    float*  s_dst   = (float*)(ws + 25362432);          // 65,536 B
    float*  den_part= (float*)(ws + 25427968);          // 64*16384*4 = 4,194,304 B

    k1_prep<<<256, 256, 0, stream>>>(W, WT);
    k2_whgemm<<<512, 256, 0, stream>>>(x, WT, a_w, Wh, s_src, s_dst);
    k4_den<<<1024, 256, 0, stream>>>(A, s_src, s_dst, a_b, den_part);
    k5_wht<<<dim3(32, 4, 8), 256, 0, stream>>>(Wh, den_part, WhT);
    k6_out<<<1024, 256, 0, stream>>>(A, WhT, s_src, s_dst, a_b, out);
}